// Round 9
// baseline (239.943 us; speedup 1.0000x reference)
//
#include <hip/hip_runtime.h>

// FiringRateModel, yy-recurrence, 16 lanes/chain, 4 states/lane, 2 waves/SIMD.
//   sigma'_t = d*sigma'_{t-1} + c_t*A' + f_{t-1}*B'   (A'=0.01*d*aw, B'=0.01*d*bw)
//   yy_{t+1} = Sum(sigma'_t) + c_{t+1}*SA' + f_t*SB'      (yy = 0.01*z - gb/100,
//              gb shift-folded into poly coeffs)
//   f_t = 400*rcp(1+exp2(Q(yy_t))) - 200,  Q coeffs pre-scaled by -2*log2(e)
// R8: κ=4 chains/wave at 2048 waves (2/SIMD) — same total issue as R7's
// κ=8 @ 1/SIMD, but two independent HW-interleaved streams hide each
// other's serial-chain bubbles (act latency + DPP hazards).
// Capture via bfi lane masks; ONE store per 16 steps; zero EXEC writes.
// allreduce16 = 4 fused DPP adds (quad_perm x1/x2, row_ror:4, row_ror:8).

#define TT 2048
#define BB 8192

typedef float v2f __attribute__((ext_vector_type(2)));

__device__ __forceinline__ float dpp_add_x1(float z) {
    float o;
    asm("v_add_f32 %0, %1, %2 quad_perm:[1,0,3,2] row_mask:0xf bank_mask:0xf"
        : "=v"(o) : "v"(z), "v"(z));
    return o;
}
__device__ __forceinline__ float dpp_add_x2(float z) {
    float o;
    asm("v_add_f32 %0, %1, %2 quad_perm:[2,3,0,1] row_mask:0xf bank_mask:0xf"
        : "=v"(o) : "v"(z), "v"(z));
    return o;
}
__device__ __forceinline__ float dpp_add_r4(float z) {
    float o;
    asm("v_add_f32 %0, %1, %2 row_ror:4 row_mask:0xf bank_mask:0xf"
        : "=v"(o) : "v"(z), "v"(z));
    return o;
}
__device__ __forceinline__ float dpp_add_r8(float z) {
    float o;
    asm("v_add_f32 %0, %1, %2 row_ror:8 row_mask:0xf bank_mask:0xf"
        : "=v"(o) : "v"(z), "v"(z));
    return o;
}
__device__ __forceinline__ float allreduce16(float z) {
    z = dpp_add_x1(z);
    z = dpp_add_x2(z);
    z = dpp_add_r4(z);
    z = dpp_add_r8(z);
    return z;
}

// branchless capture: fkeep = mk ? nf : of as v_bfi_b32
__device__ __forceinline__ float bfi_keep(unsigned mk, float nf, float of) {
    unsigned r = (__float_as_uint(nf) & mk) | (__float_as_uint(of) & ~mk);
    return __uint_as_float(r);
}

// One step. sg-update (dep: f_{t-1}) first, activation (dep: yy_t) second.
#define STEP(ccur, cnext, so, FIN, FOUT) do {                           \
    v2f f2 = { FIN, FIN };                                              \
    v2f c2 = { (ccur), (ccur) };                                        \
    sg0 = __builtin_elementwise_fma(d0, sg0,                            \
            __builtin_elementwise_fma(c2, A0, f2 * B0));                \
    sg1 = __builtin_elementwise_fma(d1, sg1,                            \
            __builtin_elementwise_fma(c2, A1, f2 * B1));                \
    v2f ss = sg0 + sg1;                                                 \
    float Sr = allreduce16(ss.x + ss.y);                                \
    float base = fmaf((cnext), SAp, Sr);                                \
    float x2 = yy * yy;                                                 \
    float t1 = fmaf(q5, yy, q4);                                        \
    float t2 = fmaf(q3, yy, q2);                                        \
    float t3 = fmaf(q1, yy, q0);                                        \
    float pl = fmaf(t1, x2, t2);                                        \
    pl = fmaf(pl, x2, t3);                                              \
    pl = fminf(pl, 0.0f);            /* coeffs carry -2*log2e */        \
    float ee = __builtin_amdgcn_exp2f(pl);                              \
    FOUT = fmaf(__builtin_amdgcn_rcpf(1.0f + ee), 400.0f, -200.0f);     \
    yy = fmaf(FOUT, SBp, base);                                         \
    fkeep = bfi_keep(msk[(so) & 15], FOUT, fkeep);                      \
} while (0)

// batched store: all 64 lanes, no exec mask; lane g writes step t0+g
#define FLUSH() do {                                                    \
    *optr = fkeep;                                                      \
    optr += 16 * BB;                                                    \
} while (0)

__global__ __launch_bounds__(256, 2) void frm_kernel(
    const float* __restrict__ cur, const float* __restrict__ fs0,
    const float* __restrict__ av,  const float* __restrict__ bv,
    const float* __restrict__ wv,  const float* __restrict__ dsv,
    const float* __restrict__ pcv, const float* __restrict__ gbv,
    float* __restrict__ outp)
{
    const int tid   = blockIdx.x * 256 + threadIdx.x;
    const int chain = tid >> 4;               // batch index b (0..8191)
    const int g     = threadIdx.x & 15;       // lane within 16-lane row

    const int n0 = g * 4;                     // this lane's 4 state indices
    const float w0 = wv[n0+0], w1 = wv[n0+1], w2 = wv[n0+2], w3 = wv[n0+3];
    const float dk0 = 1.0f - dsv[n0+0], dk1 = 1.0f - dsv[n0+1];
    const float dk2 = 1.0f - dsv[n0+2], dk3 = 1.0f - dsv[n0+3];
    // 0.01 (the /MAX_I) folded into aw/bw:
    const float ak0 = 0.01f*av[n0+0]*w0, ak1 = 0.01f*av[n0+1]*w1;
    const float ak2 = 0.01f*av[n0+2]*w2, ak3 = 0.01f*av[n0+3]*w3;
    const float bk0 = 10.0f*bv[n0+0]*w0, bk1 = 10.0f*bv[n0+1]*w1;  // 1000*0.01
    const float bk2 = 10.0f*bv[n0+2]*w2, bk3 = 10.0f*bv[n0+3]*w3;

    const v2f d0 = {dk0, dk1}, d1 = {dk2, dk3};
    const v2f A0 = {dk0*ak0, dk1*ak1}, A1 = {dk2*ak2, dk3*ak3};
    const v2f B0 = {dk0*bk0, dk1*bk1}, B1 = {dk2*bk2, dk3*bk3};

    const float SAp = allreduce16((ak0+ak1)+(ak2+ak3));
    const float SBp = allreduce16((bk0+bk1)+(bk2+bk3));

    // poly coeffs: squared, scaled by -2*log2(e)
    const float M = -2.8853900817779268f;
    float c0 = M*pcv[0]*pcv[0], c1 = M*pcv[1]*pcv[1], c2c = M*pcv[2]*pcv[2];
    float c3 = M*pcv[3]*pcv[3], c4 = M*pcv[4]*pcv[4], c5 = M*pcv[5]*pcv[5];
    // shift-fold: Q(y) = P(y + s), s = -gb*0.01 (Horner synthetic shift)
    const float s = -gbv[0] * 0.01f;
    {
        c4 = fmaf(c5, s, c4); c3 = fmaf(c4, s, c3); c2c = fmaf(c3, s, c2c);
        c1 = fmaf(c2c, s, c1); c0 = fmaf(c1, s, c0);
        c4 = fmaf(c5, s, c4); c3 = fmaf(c4, s, c3); c2c = fmaf(c3, s, c2c);
        c1 = fmaf(c2c, s, c1);
        c4 = fmaf(c5, s, c4); c3 = fmaf(c4, s, c3); c2c = fmaf(c3, s, c2c);
        c4 = fmaf(c5, s, c4); c3 = fmaf(c4, s, c3);
        c4 = fmaf(c5, s, c4);
    }
    const float q0 = c0, q1 = c1, q2 = c2c, q3 = c3, q4 = c4, q5 = c5;

    // capture masks: all-ones when g == k (v_bfi operand)
    unsigned msk[16];
#pragma unroll
    for (int k = 0; k < 16; ++k) msk[k] = (g == k) ? 0xFFFFFFFFu : 0u;

    float fA = fs0[chain];
    float fB;
    float fkeep = 0.0f;
    v2f sg0 = {0,0}, sg1 = {0,0};

    const float* cpt = cur + chain;
    float* optr = outp + chain + g * BB;      // lane g's slot in the 16-step batch

    // prefetch first 16 currents (distance-16 pipeline, two 8-wide banks)
    float P0 = cpt[0*BB], P1 = cpt[1*BB], P2 = cpt[2*BB], P3 = cpt[3*BB];
    float P4 = cpt[4*BB], P5 = cpt[5*BB], P6 = cpt[6*BB], P7 = cpt[7*BB];
    float Q0 = cpt[8*BB], Q1 = cpt[9*BB], Q2 = cpt[10*BB], Q3 = cpt[11*BB];
    float Q4 = cpt[12*BB], Q5 = cpt[13*BB], Q6 = cpt[14*BB], Q7 = cpt[15*BB];

    // yy_0 = 0.01*(c_0*SA + fs0*SB)  (sigma_{-1}=0; SAp/SBp carry the 0.01)
    float yy = fmaf(fA, SBp, P0 * SAp);

    int obase = 0;
    for (int t = 0; t + 32 <= TT; t += 16) {
        STEP(P0, P1, 0, fA, fB);  STEP(P1, P2, 1, fB, fA);
        STEP(P2, P3, 2, fA, fB);  STEP(P3, P4, 3, fB, fA);
        STEP(P4, P5, 4, fA, fB);  STEP(P5, P6, 5, fB, fA);
        STEP(P6, P7, 6, fA, fB);  STEP(P7, Q0, 7, fB, fA);
        P0 = cpt[obase + 16*BB]; P1 = cpt[obase + 17*BB];
        P2 = cpt[obase + 18*BB]; P3 = cpt[obase + 19*BB];
        P4 = cpt[obase + 20*BB]; P5 = cpt[obase + 21*BB];
        P6 = cpt[obase + 22*BB]; P7 = cpt[obase + 23*BB];
        STEP(Q0, Q1, 8, fA, fB);  STEP(Q1, Q2, 9, fB, fA);
        STEP(Q2, Q3, 10, fA, fB); STEP(Q3, Q4, 11, fB, fA);
        STEP(Q4, Q5, 12, fA, fB); STEP(Q5, Q6, 13, fB, fA);
        STEP(Q6, Q7, 14, fA, fB); STEP(Q7, P0, 15, fB, fA);
        FLUSH();
        Q0 = cpt[obase + 24*BB]; Q1 = cpt[obase + 25*BB];
        Q2 = cpt[obase + 26*BB]; Q3 = cpt[obase + 27*BB];
        Q4 = cpt[obase + 28*BB]; Q5 = cpt[obase + 29*BB];
        Q6 = cpt[obase + 30*BB]; Q7 = cpt[obase + 31*BB];
        obase += 16 * BB;
    }
    // epilogue: last 16 steps entirely from registers
    STEP(P0, P1, 0, fA, fB);  STEP(P1, P2, 1, fB, fA);
    STEP(P2, P3, 2, fA, fB);  STEP(P3, P4, 3, fB, fA);
    STEP(P4, P5, 4, fA, fB);  STEP(P5, P6, 5, fB, fA);
    STEP(P6, P7, 6, fA, fB);  STEP(P7, Q0, 7, fB, fA);
    STEP(Q0, Q1, 8, fA, fB);  STEP(Q1, Q2, 9, fB, fA);
    STEP(Q2, Q3, 10, fA, fB); STEP(Q3, Q4, 11, fB, fA);
    STEP(Q4, Q5, 12, fA, fB); STEP(Q5, Q6, 13, fB, fA);
    STEP(Q6, Q7, 14, fA, fB); STEP(Q7, 0.0f, 15, fB, fA);
    FLUSH();
}

extern "C" void kernel_launch(void* const* d_in, const int* in_sizes, int n_in,
                              void* d_out, int out_size, void* d_ws, size_t ws_size,
                              hipStream_t stream) {
    const float* cur = (const float*)d_in[0];
    const float* fs0 = (const float*)d_in[1];
    const float* a   = (const float*)d_in[2];
    const float* b   = (const float*)d_in[3];
    const float* w   = (const float*)d_in[4];
    const float* ds  = (const float*)d_in[5];
    const float* pc  = (const float*)d_in[6];
    const float* gb  = (const float*)d_in[7];
    float* out = (float*)d_out;

    const int threads = 256;
    const int grid = (BB * 16) / threads;  // 512 blocks = 2048 waves = 2/SIMD
    frm_kernel<<<grid, threads, 0, stream>>>(cur, fs0, a, b, w, ds, pc, gb, out);
}

// Round 10
// 167.342 us; speedup vs baseline: 1.4338x; 1.4338x over previous
//
#include <hip/hip_runtime.h>

// FiringRateModel, yy-recurrence, 8 lanes/chain, 8 states/lane (R7 core).
//   sigma'_t = d*sigma'_{t-1} + c_t*A' + f_{t-1}*B'   (A'=0.01*d*aw, B'=0.01*d*bw)
//   yy_{t+1} = Sum(sigma'_t) + c_{t+1}*SA' + f_t*SB'
//   f_t = 400*rcp(1+exp2(Q(yy_t))) - 200   (Q: shifted, -2log2e-scaled coeffs)
// R9: STEP body hand-interleaved — activation's 11-op dependent chain is
// woven 1:1 with the independent sg/pk ops so in-order issue fills the
// act chain's latency gaps; the 3-DPP reduce sits at the tail where the
// NEXT step's sg ops (dep only on FOUT) cover it.
// bfi capture, 1 store/8 steps, zero EXEC writes. 1024 waves = 1/SIMD.

#define TT 2048
#define BB 8192

typedef float v2f __attribute__((ext_vector_type(2)));

__device__ __forceinline__ float dpp_add_x1(float z) {
    float o;
    asm("v_add_f32 %0, %1, %2 quad_perm:[1,0,3,2] row_mask:0xf bank_mask:0xf"
        : "=v"(o) : "v"(z), "v"(z));
    return o;
}
__device__ __forceinline__ float dpp_add_x2(float z) {
    float o;
    asm("v_add_f32 %0, %1, %2 quad_perm:[2,3,0,1] row_mask:0xf bank_mask:0xf"
        : "=v"(o) : "v"(z), "v"(z));
    return o;
}
__device__ __forceinline__ float dpp_add_r8(float z) {
    float o;
    asm("v_add_f32 %0, %1, %2 row_ror:8 row_mask:0xf bank_mask:0xf"
        : "=v"(o) : "v"(z), "v"(z));
    return o;
}

// branchless capture: fkeep = mk ? nf : of as v_bfi_b32
__device__ __forceinline__ float bfi_keep(unsigned mk, float nf, float of) {
    unsigned r = (__float_as_uint(nf) & mk) | (__float_as_uint(of) & ~mk);
    return __uint_as_float(r);
}

// One step, act chain interleaved with sg/pk ops.
#define STEP(ccur, cnext, so, FIN, FOUT) do {                           \
    float x2 = yy * yy;                          /* act */              \
    v2f f2 = { FIN, FIN };                                              \
    v2f c2 = { (ccur), (ccur) };                                        \
    float t1 = fmaf(q5, yy, q4);                 /* act */              \
    v2f u0 = __builtin_elementwise_fma(c2, A0, f2 * B0);                \
    float t2 = fmaf(q3, yy, q2);                 /* act */              \
    v2f u1 = __builtin_elementwise_fma(c2, A1, f2 * B1);                \
    float t3 = fmaf(q1, yy, q0);                 /* act */              \
    v2f u2 = __builtin_elementwise_fma(c2, A2, f2 * B2);                \
    float pl = fmaf(t1, x2, t2);                 /* act */              \
    v2f u3 = __builtin_elementwise_fma(c2, A3, f2 * B3);                \
    pl = fmaf(pl, x2, t3);                       /* act */              \
    sg0 = __builtin_elementwise_fma(d0, sg0, u0);                       \
    pl = fminf(pl, 0.0f);                        /* act */              \
    sg1 = __builtin_elementwise_fma(d1, sg1, u1);                       \
    float ee = __builtin_amdgcn_exp2f(pl);       /* act trans */        \
    sg2 = __builtin_elementwise_fma(d2, sg2, u2);                       \
    sg3 = __builtin_elementwise_fma(d3, sg3, u3);                       \
    float eo = 1.0f + ee;                        /* act */              \
    v2f ssa = sg0 + sg1;                                                \
    v2f ssb = sg2 + sg3;                                                \
    float er = __builtin_amdgcn_rcpf(eo);        /* act trans */        \
    v2f ss = ssa + ssb;                                                 \
    float s01 = ss.x + ss.y;                                            \
    FOUT = fmaf(er, 400.0f, -200.0f);            /* act done */         \
    float r1 = dpp_add_x1(s01);                                         \
    fkeep = bfi_keep(msk[(so) & 7], FOUT, fkeep);                       \
    float r2 = dpp_add_x2(r1);                                          \
    float r3 = dpp_add_r8(r2);                                          \
    float base = fmaf((cnext), SAp, r3);                                \
    yy = fmaf(FOUT, SBp, base);                                         \
} while (0)

// batched store: all 64 lanes, no exec mask; lane h writes step t0+h
#define FLUSH() do {                                                    \
    *optr = fkeep;                                                      \
    optr += 8 * BB;                                                     \
} while (0)

__global__ __launch_bounds__(256, 1) void frm_kernel(
    const float* __restrict__ cur, const float* __restrict__ fs0,
    const float* __restrict__ av,  const float* __restrict__ bv,
    const float* __restrict__ wv,  const float* __restrict__ dsv,
    const float* __restrict__ pcv, const float* __restrict__ gbv,
    float* __restrict__ outp)
{
    const int tid  = blockIdx.x * 256 + threadIdx.x;
    const int lane = threadIdx.x & 15;        // lane within DPP row
    const int row  = tid >> 4;                // 16-lane row id (0..4095)
    const int sub  = (lane >> 2) & 1;         // chain = quad parity
    const int chain = row * 2 + sub;          // batch index b (0..8191)
    const int h    = ((lane >> 3) << 2) | (lane & 3);  // state-group / store slot 0..7

    const int n0 = h * 8;                     // this lane's 8 state indices
    float wk0 = wv[n0+0], wk1 = wv[n0+1], wk2 = wv[n0+2], wk3 = wv[n0+3];
    float wk4 = wv[n0+4], wk5 = wv[n0+5], wk6 = wv[n0+6], wk7 = wv[n0+7];
    float dk0 = 1.0f-dsv[n0+0], dk1 = 1.0f-dsv[n0+1], dk2 = 1.0f-dsv[n0+2], dk3 = 1.0f-dsv[n0+3];
    float dk4 = 1.0f-dsv[n0+4], dk5 = 1.0f-dsv[n0+5], dk6 = 1.0f-dsv[n0+6], dk7 = 1.0f-dsv[n0+7];
    // 0.01 (the /MAX_I) folded into aw/bw:
    float ak0 = 0.01f*av[n0+0]*wk0, ak1 = 0.01f*av[n0+1]*wk1;
    float ak2 = 0.01f*av[n0+2]*wk2, ak3 = 0.01f*av[n0+3]*wk3;
    float ak4 = 0.01f*av[n0+4]*wk4, ak5 = 0.01f*av[n0+5]*wk5;
    float ak6 = 0.01f*av[n0+6]*wk6, ak7 = 0.01f*av[n0+7]*wk7;
    float bk0 = 10.0f*bv[n0+0]*wk0, bk1 = 10.0f*bv[n0+1]*wk1;   // 1000*0.01
    float bk2 = 10.0f*bv[n0+2]*wk2, bk3 = 10.0f*bv[n0+3]*wk3;
    float bk4 = 10.0f*bv[n0+4]*wk4, bk5 = 10.0f*bv[n0+5]*wk5;
    float bk6 = 10.0f*bv[n0+6]*wk6, bk7 = 10.0f*bv[n0+7]*wk7;

    const v2f d0 = {dk0, dk1}, d1 = {dk2, dk3}, d2 = {dk4, dk5}, d3 = {dk6, dk7};
    const v2f A0 = {dk0*ak0, dk1*ak1}, A1 = {dk2*ak2, dk3*ak3};
    const v2f A2 = {dk4*ak4, dk5*ak5}, A3 = {dk6*ak6, dk7*ak7};
    const v2f B0 = {dk0*bk0, dk1*bk1}, B1 = {dk2*bk2, dk3*bk3};
    const v2f B2 = {dk4*bk4, dk5*bk5}, B3 = {dk6*bk6, dk7*bk7};

    float sa8 = ((ak0+ak1)+(ak2+ak3)) + ((ak4+ak5)+(ak6+ak7));
    float sb8 = ((bk0+bk1)+(bk2+bk3)) + ((bk4+bk5)+(bk6+bk7));
    sa8 = dpp_add_x1(sa8); sa8 = dpp_add_x2(sa8); sa8 = dpp_add_r8(sa8);
    sb8 = dpp_add_x1(sb8); sb8 = dpp_add_x2(sb8); sb8 = dpp_add_r8(sb8);
    const float SAp = sa8, SBp = sb8;

    // poly coeffs: squared, scaled by -2*log2(e)
    const float M = -2.8853900817779268f;
    float c0 = M*pcv[0]*pcv[0], c1 = M*pcv[1]*pcv[1], c2c = M*pcv[2]*pcv[2];
    float c3 = M*pcv[3]*pcv[3], c4 = M*pcv[4]*pcv[4], c5 = M*pcv[5]*pcv[5];
    // shift-fold: Q(y) = P(y + s), s = -gb*0.01 (Horner synthetic shift)
    const float s = -gbv[0] * 0.01f;
    {
        c4 = fmaf(c5, s, c4); c3 = fmaf(c4, s, c3); c2c = fmaf(c3, s, c2c);
        c1 = fmaf(c2c, s, c1); c0 = fmaf(c1, s, c0);
        c4 = fmaf(c5, s, c4); c3 = fmaf(c4, s, c3); c2c = fmaf(c3, s, c2c);
        c1 = fmaf(c2c, s, c1);
        c4 = fmaf(c5, s, c4); c3 = fmaf(c4, s, c3); c2c = fmaf(c3, s, c2c);
        c4 = fmaf(c5, s, c4); c3 = fmaf(c4, s, c3);
        c4 = fmaf(c5, s, c4);
    }
    const float q0 = c0, q1 = c1, q2 = c2c, q3 = c3, q4 = c4, q5 = c5;

    // capture masks: all-ones when h == k (v_bfi operand)
    unsigned msk[8];
#pragma unroll
    for (int k = 0; k < 8; ++k) msk[k] = (h == k) ? 0xFFFFFFFFu : 0u;

    float fA = fs0[chain];
    float fB;
    float fkeep = 0.0f;
    v2f sg0 = {0,0}, sg1 = {0,0}, sg2 = {0,0}, sg3 = {0,0};

    const float* cpt = cur + chain;
    float* optr = outp + chain + h * BB;      // lane h's slot in the 8-step batch

    // prefetch first 16 currents (distance-16 pipeline, two 8-wide banks)
    float P0 = cpt[0*BB], P1 = cpt[1*BB], P2 = cpt[2*BB], P3 = cpt[3*BB];
    float P4 = cpt[4*BB], P5 = cpt[5*BB], P6 = cpt[6*BB], P7 = cpt[7*BB];
    float Q0 = cpt[8*BB], Q1 = cpt[9*BB], Q2 = cpt[10*BB], Q3 = cpt[11*BB];
    float Q4 = cpt[12*BB], Q5 = cpt[13*BB], Q6 = cpt[14*BB], Q7 = cpt[15*BB];

    // yy_0 = 0.01*(c_0*SA + fs0*SB)  (sigma_{-1}=0; SAp/SBp carry the 0.01)
    float yy = fmaf(fA, SBp, P0 * SAp);

    int obase = 0;
    for (int t = 0; t + 32 <= TT; t += 16) {
        STEP(P0, P1, 0, fA, fB);  STEP(P1, P2, 1, fB, fA);
        STEP(P2, P3, 2, fA, fB);  STEP(P3, P4, 3, fB, fA);
        STEP(P4, P5, 4, fA, fB);  STEP(P5, P6, 5, fB, fA);
        STEP(P6, P7, 6, fA, fB);  STEP(P7, Q0, 7, fB, fA);
        FLUSH();
        P0 = cpt[obase + 16*BB]; P1 = cpt[obase + 17*BB];
        P2 = cpt[obase + 18*BB]; P3 = cpt[obase + 19*BB];
        P4 = cpt[obase + 20*BB]; P5 = cpt[obase + 21*BB];
        P6 = cpt[obase + 22*BB]; P7 = cpt[obase + 23*BB];
        STEP(Q0, Q1, 8, fA, fB);  STEP(Q1, Q2, 9, fB, fA);
        STEP(Q2, Q3, 10, fA, fB); STEP(Q3, Q4, 11, fB, fA);
        STEP(Q4, Q5, 12, fA, fB); STEP(Q5, Q6, 13, fB, fA);
        STEP(Q6, Q7, 14, fA, fB); STEP(Q7, P0, 15, fB, fA);
        FLUSH();
        Q0 = cpt[obase + 24*BB]; Q1 = cpt[obase + 25*BB];
        Q2 = cpt[obase + 26*BB]; Q3 = cpt[obase + 27*BB];
        Q4 = cpt[obase + 28*BB]; Q5 = cpt[obase + 29*BB];
        Q6 = cpt[obase + 30*BB]; Q7 = cpt[obase + 31*BB];
        obase += 16 * BB;
    }
    // epilogue: last 16 steps entirely from registers
    STEP(P0, P1, 0, fA, fB);  STEP(P1, P2, 1, fB, fA);
    STEP(P2, P3, 2, fA, fB);  STEP(P3, P4, 3, fB, fA);
    STEP(P4, P5, 4, fA, fB);  STEP(P5, P6, 5, fB, fA);
    STEP(P6, P7, 6, fA, fB);  STEP(P7, Q0, 7, fB, fA);
    FLUSH();
    STEP(Q0, Q1, 8, fA, fB);  STEP(Q1, Q2, 9, fB, fA);
    STEP(Q2, Q3, 10, fA, fB); STEP(Q3, Q4, 11, fB, fA);
    STEP(Q4, Q5, 12, fA, fB); STEP(Q5, Q6, 13, fB, fA);
    STEP(Q6, Q7, 14, fA, fB); STEP(Q7, 0.0f, 15, fB, fA);
    FLUSH();
}

extern "C" void kernel_launch(void* const* d_in, const int* in_sizes, int n_in,
                              void* d_out, int out_size, void* d_ws, size_t ws_size,
                              hipStream_t stream) {
    const float* cur = (const float*)d_in[0];
    const float* fs0 = (const float*)d_in[1];
    const float* a   = (const float*)d_in[2];
    const float* b   = (const float*)d_in[3];
    const float* w   = (const float*)d_in[4];
    const float* ds  = (const float*)d_in[5];
    const float* pc  = (const float*)d_in[6];
    const float* gb  = (const float*)d_in[7];
    float* out = (float*)d_out;

    const int threads = 256;
    const int grid = (BB * 8) / threads;   // 256 blocks = 1024 waves = 1/SIMD
    frm_kernel<<<grid, threads, 0, stream>>>(cur, fs0, a, b, w, ds, pc, gb, out);
}